// Round 1
// baseline (3379.402 us; speedup 1.0000x reference)
//
#include <hip/hip_runtime.h>
#include <hip/hip_bf16.h>

// SWIN attention, fp32 baseline.
// M=32, H=W=64, D=256, 8x8 windows (64 tokens), NW=64 windows/image -> 2048 windows,
// NH=8 heads, hd=32. Two passes: unshifted (no mask), shifted by (4,4) with swin mask.
// Pipeline per pass: qkv GEMM -> per-(window,head) attention -> out-proj GEMM.
// y (pass-1 output) lives in d_out; pass-2 gathers from it and overwrites it.

#define SCALE 0.17677669529663687f  // 1/sqrt(32)
#define NEGM  -1e9f

__device__ __forceinline__ void win_coords(int pass, int gw, int s,
                                           int& m, int& h, int& w) {
  m = gw >> 6;
  int wy = (gw >> 3) & 7, wx = gw & 7;
  h = wy * 8 + (s >> 3);
  w = wx * 8 + (s & 7);
  if (pass) { h = (h + 4) & 63; w = (w + 4) & 63; }
}

__device__ __forceinline__ int region_id(int wy, int wx, int s) {
  int rh = (wy == 7) ? (((s >> 3) >= 4) ? 2 : 1) : 0;
  int rw = (wx == 7) ? (((s & 7) >= 4) ? 2 : 1) : 0;
  return rh * 3 + rw;
}

// ---------------------------------------------------------------------------
// Kernel A: qkv = gather(window tokens) @ w_qkv + b_qkv
// grid: (CW/2) * 6 blocks; block covers 128 rows (2 windows) x 128 cols.
// ---------------------------------------------------------------------------
__global__ __launch_bounds__(256) void qkv_kernel(
    const float* __restrict__ src, const float* __restrict__ wqkv,
    const float* __restrict__ bqkv, float* __restrict__ qkv,
    int w0, int pass) {
  __shared__ float Ast[64][128];  // [kk][row]  (transposed A tile)
  __shared__ float Bs[64][128];   // [kk][col]
  const int t = threadIdx.x;
  const int wpair = blockIdx.x / 6;
  const int ct = blockIdx.x % 6;
  const int gw0 = w0 + wpair * 2;

  // A-staging assignment: row lr, 32-float half lf
  const int lr = t >> 1;
  const int lf = (t & 1) * 32;
  int m, h, w;
  win_coords(pass, gw0 + (lr >> 6), lr & 63, m, h, w);
  const float* arow = src + (size_t)((m * 64 + h) * 64 + w) * 256;

  // B-staging assignment
  const int lkb = t >> 2;
  const int lcb = (t & 3) * 32;

  const int ty = t >> 4, tx = t & 15;
  float acc[8][8] = {};

  for (int kc = 0; kc < 4; ++kc) {
    const int k0 = kc * 64;
#pragma unroll
    for (int u = 0; u < 8; ++u) {
      float4 v = *(const float4*)(arow + k0 + lf + u * 4);
      int kk = lf + u * 4;
      Ast[kk + 0][lr] = v.x;
      Ast[kk + 1][lr] = v.y;
      Ast[kk + 2][lr] = v.z;
      Ast[kk + 3][lr] = v.w;
    }
    const float* brow = wqkv + (size_t)(k0 + lkb) * 768 + ct * 128 + lcb;
#pragma unroll
    for (int u = 0; u < 8; ++u) {
      *(float4*)&Bs[lkb][lcb + u * 4] = *(const float4*)(brow + u * 4);
    }
    __syncthreads();
#pragma unroll
    for (int kk = 0; kk < 64; ++kk) {
      float4 a0 = *(float4*)&Ast[kk][ty * 4];
      float4 a1 = *(float4*)&Ast[kk][64 + ty * 4];
      float4 b0 = *(float4*)&Bs[kk][tx * 4];
      float4 b1 = *(float4*)&Bs[kk][64 + tx * 4];
      float av[8] = {a0.x, a0.y, a0.z, a0.w, a1.x, a1.y, a1.z, a1.w};
      float bv[8] = {b0.x, b0.y, b0.z, b0.w, b1.x, b1.y, b1.z, b1.w};
#pragma unroll
      for (int i = 0; i < 8; ++i)
#pragma unroll
        for (int j = 0; j < 8; ++j) acc[i][j] += av[i] * bv[j];
    }
    __syncthreads();
  }

  float bias[8];
#pragma unroll
  for (int j = 0; j < 8; ++j) {
    int c = (j < 4) ? (tx * 4 + j) : (64 + tx * 4 + (j - 4));
    bias[j] = bqkv[ct * 128 + c];
  }
#pragma unroll
  for (int i = 0; i < 8; ++i) {
    const int r = (i < 4) ? (ty * 4 + i) : (64 + ty * 4 + (i - 4));
    const int wi = (gw0 - w0) + (r >> 6);
    float* orow = qkv + ((size_t)wi * 64 + (r & 63)) * 768 + ct * 128;
    *(float4*)(orow + tx * 4) =
        make_float4(acc[i][0] + bias[0], acc[i][1] + bias[1],
                    acc[i][2] + bias[2], acc[i][3] + bias[3]);
    *(float4*)(orow + 64 + tx * 4) =
        make_float4(acc[i][4] + bias[4], acc[i][5] + bias[5],
                    acc[i][6] + bias[6], acc[i][7] + bias[7]);
  }
}

// ---------------------------------------------------------------------------
// Kernel B: per (window, head) attention. grid: CW*8 blocks, 256 threads.
// ---------------------------------------------------------------------------
__global__ __launch_bounds__(256) void attn_kernel(
    const float* __restrict__ qkv, float* __restrict__ attn_out,
    int w0, int pass) {
  __shared__ float Qst[32][68];  // [kk][i]
  __shared__ float Kst[32][68];  // [kk][j]
  __shared__ float Vs[64][36];   // [j][d]
  __shared__ float At[64][68];   // scores^T then attn^T: [j][i]
  const int t = threadIdx.x;
  const int wi = blockIdx.x >> 3;
  const int hh = blockIdx.x & 7;
  const float* base = qkv + (size_t)wi * (64 * 768) + hh * 32;

  // stage Q,K (transposed) and V
  {
    const int s = t >> 2, c0 = (t & 3) * 8;
    const float* qrow = base + (size_t)s * 768;
    float4 q0 = *(const float4*)(qrow + c0);
    float4 q1 = *(const float4*)(qrow + c0 + 4);
    float4 ka = *(const float4*)(qrow + 256 + c0);
    float4 kb = *(const float4*)(qrow + 256 + c0 + 4);
    float4 va = *(const float4*)(qrow + 512 + c0);
    float4 vb = *(const float4*)(qrow + 512 + c0 + 4);
    Qst[c0 + 0][s] = q0.x; Qst[c0 + 1][s] = q0.y;
    Qst[c0 + 2][s] = q0.z; Qst[c0 + 3][s] = q0.w;
    Qst[c0 + 4][s] = q1.x; Qst[c0 + 5][s] = q1.y;
    Qst[c0 + 6][s] = q1.z; Qst[c0 + 7][s] = q1.w;
    Kst[c0 + 0][s] = ka.x; Kst[c0 + 1][s] = ka.y;
    Kst[c0 + 2][s] = ka.z; Kst[c0 + 3][s] = ka.w;
    Kst[c0 + 4][s] = kb.x; Kst[c0 + 5][s] = kb.y;
    Kst[c0 + 6][s] = kb.z; Kst[c0 + 7][s] = kb.w;
    *(float4*)&Vs[s][c0] = va;
    *(float4*)&Vs[s][c0 + 4] = vb;
  }
  __syncthreads();

  // scores: sc[ii][jj] over rows i = 4*ti.., cols j = 4*tj..
  const int ti = t >> 4, tj = t & 15;
  float sc[4][4] = {};
#pragma unroll
  for (int kk = 0; kk < 32; ++kk) {
    float4 a = *(float4*)&Qst[kk][ti * 4];
    float4 b = *(float4*)&Kst[kk][tj * 4];
    float av[4] = {a.x, a.y, a.z, a.w};
    float bv[4] = {b.x, b.y, b.z, b.w};
#pragma unroll
    for (int ii = 0; ii < 4; ++ii)
#pragma unroll
      for (int jj = 0; jj < 4; ++jj) sc[ii][jj] += av[ii] * bv[jj];
  }
  {
    const int gw = w0 + wi;
    const int wy = (gw >> 3) & 7, wx = gw & 7;
#pragma unroll
    for (int jj = 0; jj < 4; ++jj) {
      const int j = tj * 4 + jj;
      const int idj = region_id(wy, wx, j);
#pragma unroll
      for (int ii = 0; ii < 4; ++ii) {
        const int i = ti * 4 + ii;
        float v = sc[ii][jj] * SCALE;
        if (pass && region_id(wy, wx, i) != idj) v += NEGM;
        At[j][i] = v;  // store transposed
      }
    }
  }
  __syncthreads();

  // softmax over j for each row i (column of At); one thread per row
  if (t < 64) {
    float mx = -1e30f;
    for (int j = 0; j < 64; ++j) mx = fmaxf(mx, At[j][t]);
    float sm = 0.f;
    for (int j = 0; j < 64; ++j) {
      float e = __expf(At[j][t] - mx);
      At[j][t] = e;
      sm += e;
    }
    float inv = 1.f / sm;
    for (int j = 0; j < 64; ++j) At[j][t] *= inv;
  }
  __syncthreads();

  // PV: out[i][d] = sum_j At[j][i] * Vs[j][d]; thread: rows 4*ti.., d pair 2*td
  const int td = t & 15;
  float ov[4][2] = {};
#pragma unroll 8
  for (int j = 0; j < 64; ++j) {
    float4 a = *(float4*)&At[j][ti * 4];
    float2 v = *(float2*)&Vs[j][td * 2];
    ov[0][0] += a.x * v.x; ov[0][1] += a.x * v.y;
    ov[1][0] += a.y * v.x; ov[1][1] += a.y * v.y;
    ov[2][0] += a.z * v.x; ov[2][1] += a.z * v.y;
    ov[3][0] += a.w * v.x; ov[3][1] += a.w * v.y;
  }
#pragma unroll
  for (int ii = 0; ii < 4; ++ii) {
    const int i = ti * 4 + ii;
    *(float2*)&attn_out[((size_t)wi * 64 + i) * 256 + hh * 32 + td * 2] =
        make_float2(ov[ii][0], ov[ii][1]);
  }
}

// ---------------------------------------------------------------------------
// Kernel C: out = attn @ w_o + b_o, scattered to image layout (+roll for pass 1)
// grid: (CW/2) * 2 blocks.
// ---------------------------------------------------------------------------
__global__ __launch_bounds__(256) void proj_kernel(
    const float* __restrict__ attn, const float* __restrict__ wo,
    const float* __restrict__ bo, float* __restrict__ out,
    int w0, int pass) {
  __shared__ float Ast[64][128];
  __shared__ float Bs[64][128];
  const int t = threadIdx.x;
  const int wpair = blockIdx.x >> 1;
  const int ct = blockIdx.x & 1;

  const int lr = t >> 1;
  const int lf = (t & 1) * 32;
  const float* arow = attn + (size_t)(wpair * 128 + lr) * 256;

  const int lkb = t >> 2;
  const int lcb = (t & 3) * 32;
  const int ty = t >> 4, tx = t & 15;
  float acc[8][8] = {};

  for (int kc = 0; kc < 4; ++kc) {
    const int k0 = kc * 64;
#pragma unroll
    for (int u = 0; u < 8; ++u) {
      float4 v = *(const float4*)(arow + k0 + lf + u * 4);
      int kk = lf + u * 4;
      Ast[kk + 0][lr] = v.x;
      Ast[kk + 1][lr] = v.y;
      Ast[kk + 2][lr] = v.z;
      Ast[kk + 3][lr] = v.w;
    }
    const float* brow = wo + (size_t)(k0 + lkb) * 256 + ct * 128 + lcb;
#pragma unroll
    for (int u = 0; u < 8; ++u) {
      *(float4*)&Bs[lkb][lcb + u * 4] = *(const float4*)(brow + u * 4);
    }
    __syncthreads();
#pragma unroll
    for (int kk = 0; kk < 64; ++kk) {
      float4 a0 = *(float4*)&Ast[kk][ty * 4];
      float4 a1 = *(float4*)&Ast[kk][64 + ty * 4];
      float4 b0 = *(float4*)&Bs[kk][tx * 4];
      float4 b1 = *(float4*)&Bs[kk][64 + tx * 4];
      float av[8] = {a0.x, a0.y, a0.z, a0.w, a1.x, a1.y, a1.z, a1.w};
      float bv[8] = {b0.x, b0.y, b0.z, b0.w, b1.x, b1.y, b1.z, b1.w};
#pragma unroll
      for (int i = 0; i < 8; ++i)
#pragma unroll
        for (int j = 0; j < 8; ++j) acc[i][j] += av[i] * bv[j];
    }
    __syncthreads();
  }

  float bias[8];
#pragma unroll
  for (int j = 0; j < 8; ++j) {
    int c = (j < 4) ? (tx * 4 + j) : (64 + tx * 4 + (j - 4));
    bias[j] = bo[ct * 128 + c];
  }
#pragma unroll
  for (int i = 0; i < 8; ++i) {
    const int r = (i < 4) ? (ty * 4 + i) : (64 + ty * 4 + (i - 4));
    const int gw = w0 + wpair * 2 + (r >> 6);
    int m, h, w;
    win_coords(pass, gw, r & 63, m, h, w);
    float* orow = out + (size_t)((m * 64 + h) * 64 + w) * 256 + ct * 128;
    *(float4*)(orow + tx * 4) =
        make_float4(acc[i][0] + bias[0], acc[i][1] + bias[1],
                    acc[i][2] + bias[2], acc[i][3] + bias[3]);
    *(float4*)(orow + 64 + tx * 4) =
        make_float4(acc[i][4] + bias[4], acc[i][5] + bias[5],
                    acc[i][6] + bias[6], acc[i][7] + bias[7]);
  }
}

// ---------------------------------------------------------------------------
extern "C" void kernel_launch(void* const* d_in, const int* in_sizes, int n_in,
                              void* d_out, int out_size, void* d_ws, size_t ws_size,
                              hipStream_t stream) {
  (void)in_sizes; (void)n_in; (void)out_size;
  const float* x    = (const float*)d_in[0];
  const float* wqkv = (const float*)d_in[1];
  const float* bqkv = (const float*)d_in[2];
  const float* wo   = (const float*)d_in[3];
  const float* bo   = (const float*)d_in[4];
  float* out = (float*)d_out;

  // Workspace chunking: per chunk of CW windows need CW*(64*768 + 64*256)*4 B.
  // S=1 needs 512 MiB; halve chunk until it fits ws_size.
  int S = 1;
  while (S < 1024 &&
         (size_t)(2048 / S) * (size_t)(196608 + 65536) > ws_size) S <<= 1;
  const int CW = 2048 / S;
  float* qkv_ws  = (float*)d_ws;
  float* attn_ws = (float*)((char*)d_ws + (size_t)CW * 196608);

  for (int pass = 0; pass < 2; ++pass) {
    const float* src = pass ? (const float*)out : x;
    for (int c = 0; c < S; ++c) {
      const int w0 = c * CW;
      qkv_kernel<<<dim3(CW / 2 * 6), dim3(256), 0, stream>>>(
          src, wqkv, bqkv, qkv_ws, w0, pass);
      attn_kernel<<<dim3(CW * 8), dim3(256), 0, stream>>>(
          qkv_ws, attn_ws, w0, pass);
      proj_kernel<<<dim3(CW / 2 * 2), dim3(256), 0, stream>>>(
          attn_ws, wo, bo, out, w0, pass);
    }
  }
}

// Round 2
// 1680.561 us; speedup vs baseline: 2.0109x; 2.0109x over previous
//
#include <hip/hip_runtime.h>
#include <hip/hip_bf16.h>

// SWIN attention, round 2: bf16 MFMA GEMMs + fp32 VALU attention core.
// M=32, H=W=64, D=256, 8x8 windows (64 tok), 2048 windows, NH=8, hd=32.
// Pipeline per pass: convert/gather(bf16) -> qkv MFMA GEMM (head-major out)
//                    -> per-(window,head) attention -> out-proj MFMA GEMM.

typedef short short8 __attribute__((ext_vector_type(8)));
typedef float floatx4 __attribute__((ext_vector_type(4)));

#define SCALE 0.17677669529663687f  // 1/sqrt(32)
#define NEGM  -1e9f

__device__ __forceinline__ void win_coords(int pass, int gw, int s,
                                           int& m, int& h, int& w) {
  m = gw >> 6;
  int wy = (gw >> 3) & 7, wx = gw & 7;
  h = wy * 8 + (s >> 3);
  w = wx * 8 + (s & 7);
  if (pass) { h = (h + 4) & 63; w = (w + 4) & 63; }
}

__device__ __forceinline__ int region_id(int wy, int wx, int s) {
  int rh = (wy == 7) ? (((s >> 3) >= 4) ? 2 : 1) : 0;
  int rw = (wx == 7) ? (((s & 7) >= 4) ? 2 : 1) : 0;
  return rh * 3 + rw;
}

__device__ __forceinline__ ushort f2b(float f) {  // RNE fp32->bf16
  uint u = __float_as_uint(f);
  return (ushort)((u + 0x7FFFu + ((u >> 16) & 1u)) >> 16);
}

__device__ __forceinline__ void unpack8(uint4 u, float* f) {
  uint w[4] = {u.x, u.y, u.z, u.w};
#pragma unroll
  for (int i = 0; i < 4; ++i) {
    f[2 * i]     = __uint_as_float(w[i] << 16);
    f[2 * i + 1] = __uint_as_float(w[i] & 0xFFFF0000u);
  }
}

// ---------------------------------------------------------------------------
// K0: transpose weights to k-contiguous bf16. blocks 0..767 -> wqkvT rows,
// 768..1023 -> woT rows.
// ---------------------------------------------------------------------------
__global__ __launch_bounds__(256) void wtrans_kernel(
    const float* __restrict__ wqkv, const float* __restrict__ wo,
    ushort* __restrict__ wqkvT, ushort* __restrict__ woT) {
  const int t = threadIdx.x, b = blockIdx.x;
  if (b < 768) {
    wqkvT[b * 256 + t] = f2b(wqkv[t * 768 + b]);
  } else {
    const int n = b - 768;
    woT[n * 256 + t] = f2b(wo[t * 256 + n]);
  }
}

// ---------------------------------------------------------------------------
// K1: gather window tokens (with pass-2 roll) + fp32->bf16.
// xw: [2048 win][64 tok][256] bf16. grid 16384 x 256 (8 rows/block).
// ---------------------------------------------------------------------------
__global__ __launch_bounds__(256) void convert_kernel(
    const float* __restrict__ src, ushort* __restrict__ xw, int pass) {
  const int t = threadIdx.x;
  const int row = blockIdx.x * 8 + (t >> 5);
  const int c = (t & 31) * 8;
  int m, h, w;
  win_coords(pass, row >> 6, row & 63, m, h, w);
  const float* s = src + (size_t)((m * 64 + h) * 64 + w) * 256 + c;
  float4 a = *(const float4*)s;
  float4 b = *(const float4*)(s + 4);
  ushort o[8] = {f2b(a.x), f2b(a.y), f2b(a.z), f2b(a.w),
                 f2b(b.x), f2b(b.y), f2b(b.z), f2b(b.w)};
  *(uint4*)(xw + (size_t)row * 256 + c) = *(uint4*)o;
}

// ---------------------------------------------------------------------------
// K2: qkv = xw @ wqkv + b, bf16 MFMA, 128x128 tile, BK=64.
// Output head-major bf16: qkvh[wi][which(3)][head(8)][s(64)][d(32)].
// grid (6 colTiles, CW/2 rowTiles) x 256. blockIdx.x fastest -> A-tile L2 reuse.
// ---------------------------------------------------------------------------
__global__ __launch_bounds__(256) void qkv_mfma_kernel(
    const ushort* __restrict__ A, const ushort* __restrict__ BT,
    const float* __restrict__ bqkv, ushort* __restrict__ qkvh) {
  __shared__ ushort As[128][72];
  __shared__ ushort Bs[128][72];
  const int t = threadIdx.x;
  const int lane = t & 63, wv = t >> 6;
  const int wm = wv >> 1, wn = wv & 1;
  const int quad = lane >> 4, l15 = lane & 15;
  const int sr = t >> 1, sh = (t & 1) * 32;
  const int bn0 = blockIdx.x * 128, row0 = blockIdx.y * 128;

  floatx4 acc[4][4];
#pragma unroll
  for (int i = 0; i < 4; ++i)
#pragma unroll
    for (int j = 0; j < 4; ++j) acc[i][j] = {0.f, 0.f, 0.f, 0.f};

  const ushort* arow = A + (size_t)(row0 + sr) * 256 + sh;
  const ushort* brow = BT + (size_t)(bn0 + sr) * 256 + sh;

  for (int kc = 0; kc < 4; ++kc) {
    const int k0 = kc * 64;
#pragma unroll
    for (int u = 0; u < 4; ++u) {
      *(uint4*)&As[sr][sh + u * 8] = *(const uint4*)(arow + k0 + u * 8);
      *(uint4*)&Bs[sr][sh + u * 8] = *(const uint4*)(brow + k0 + u * 8);
    }
    __syncthreads();
#pragma unroll
    for (int ks = 0; ks < 2; ++ks) {
      const int ko = ks * 32 + quad * 8;
      short8 af[4], bf[4];
#pragma unroll
      for (int i = 0; i < 4; ++i) {
        af[i] = *(const short8*)&As[wm * 64 + i * 16 + l15][ko];
        bf[i] = *(const short8*)&Bs[wn * 64 + i * 16 + l15][ko];
      }
#pragma unroll
      for (int mi = 0; mi < 4; ++mi)
#pragma unroll
        for (int nj = 0; nj < 4; ++nj)
          acc[mi][nj] = __builtin_amdgcn_mfma_f32_16x16x32_bf16(
              af[mi], bf[nj], acc[mi][nj], 0, 0, 0);
    }
    __syncthreads();
  }

  // epilogue: +bias, bf16, scatter head-major
  int coladdr[4];
  float bias[4];
#pragma unroll
  for (int nj = 0; nj < 4; ++nj) {
    const int n = bn0 + wn * 64 + nj * 16 + l15;
    const int which = n >> 8, head = (n >> 5) & 7, d = n & 31;
    coladdr[nj] = (which * 8 + head) * 2048 + d;
    bias[nj] = bqkv[n];
  }
#pragma unroll
  for (int mi = 0; mi < 4; ++mi)
#pragma unroll
    for (int r = 0; r < 4; ++r) {
      const int gr = row0 + wm * 64 + mi * 16 + quad * 4 + r;
      ushort* base = qkvh + (size_t)(gr >> 6) * 49152 + (gr & 63) * 32;
#pragma unroll
      for (int nj = 0; nj < 4; ++nj)
        base[coladdr[nj]] = f2b(acc[mi][nj][r] + bias[nj]);
    }
}

// ---------------------------------------------------------------------------
// K3: per (window, head) attention, fp32 VALU, bf16 head-major input.
// grid CW*8 x 256.
// ---------------------------------------------------------------------------
__global__ __launch_bounds__(256) void attn_kernel(
    const ushort* __restrict__ qkvh, float* __restrict__ attn_out,
    int w0, int pass) {
  __shared__ float Qst[32][68];  // [k][i]
  __shared__ float Kst[32][68];  // [k][j]
  __shared__ float Vs[64][36];   // [j][d]
  __shared__ float At[64][68];   // [j][i]
  const int t = threadIdx.x;
  const int wi = blockIdx.x >> 3;
  const int hh = blockIdx.x & 7;
  const ushort* base = qkvh + ((size_t)wi * 24 + hh) * 2048;

  {
    const int s = t >> 2, c0 = (t & 3) * 8;
    float fq[8], fk[8], fv[8];
    unpack8(*(const uint4*)(base + s * 32 + c0), fq);
    unpack8(*(const uint4*)(base + 16384 + s * 32 + c0), fk);
    unpack8(*(const uint4*)(base + 32768 + s * 32 + c0), fv);
#pragma unroll
    for (int i = 0; i < 8; ++i) {
      Qst[c0 + i][s] = fq[i];
      Kst[c0 + i][s] = fk[i];
      Vs[s][c0 + i] = fv[i];
    }
  }
  __syncthreads();

  const int ti = t >> 4, tj = t & 15;
  float sc[4][4] = {};
#pragma unroll
  for (int kk = 0; kk < 32; ++kk) {
    float4 a = *(float4*)&Qst[kk][ti * 4];
    float4 b = *(float4*)&Kst[kk][tj * 4];
    float av[4] = {a.x, a.y, a.z, a.w};
    float bv[4] = {b.x, b.y, b.z, b.w};
#pragma unroll
    for (int ii = 0; ii < 4; ++ii)
#pragma unroll
      for (int jj = 0; jj < 4; ++jj) sc[ii][jj] += av[ii] * bv[jj];
  }
  {
    const int gw = w0 + wi;
    const int wy = (gw >> 3) & 7, wx = gw & 7;
#pragma unroll
    for (int jj = 0; jj < 4; ++jj) {
      const int j = tj * 4 + jj;
      const int idj = region_id(wy, wx, j);
#pragma unroll
      for (int ii = 0; ii < 4; ++ii) {
        const int i = ti * 4 + ii;
        float v = sc[ii][jj] * SCALE;
        if (pass && region_id(wy, wx, i) != idj) v += NEGM;
        At[j][i] = v;
      }
    }
  }
  __syncthreads();

  if (t < 64) {
    float mx = -1e30f;
    for (int j = 0; j < 64; ++j) mx = fmaxf(mx, At[j][t]);
    float sm = 0.f;
    for (int j = 0; j < 64; ++j) {
      float e = __expf(At[j][t] - mx);
      At[j][t] = e;
      sm += e;
    }
    float inv = 1.f / sm;
    for (int j = 0; j < 64; ++j) At[j][t] *= inv;
  }
  __syncthreads();

  const int td = t & 15;
  float ov[4][2] = {};
#pragma unroll 8
  for (int j = 0; j < 64; ++j) {
    float4 a = *(float4*)&At[j][ti * 4];
    float2 v = *(float2*)&Vs[j][td * 2];
    ov[0][0] += a.x * v.x; ov[0][1] += a.x * v.y;
    ov[1][0] += a.y * v.x; ov[1][1] += a.y * v.y;
    ov[2][0] += a.z * v.x; ov[2][1] += a.z * v.y;
    ov[3][0] += a.w * v.x; ov[3][1] += a.w * v.y;
  }
#pragma unroll
  for (int ii = 0; ii < 4; ++ii) {
    const int i = ti * 4 + ii;
    *(float2*)&attn_out[((size_t)wi * 64 + i) * 256 + hh * 32 + td * 2] =
        make_float2(ov[ii][0], ov[ii][1]);
  }
}

// ---------------------------------------------------------------------------
// K4: out = attn @ w_o + b_o, bf16 MFMA, fused window-reverse(+roll) scatter.
// grid (2, CW/2) x 256.
// ---------------------------------------------------------------------------
__global__ __launch_bounds__(256) void proj_mfma_kernel(
    const float* __restrict__ attn, const ushort* __restrict__ BT,
    const float* __restrict__ bo, float* __restrict__ out,
    int w0, int pass) {
  __shared__ ushort As[128][72];
  __shared__ ushort Bs[128][72];
  const int t = threadIdx.x;
  const int lane = t & 63, wv = t >> 6;
  const int wm = wv >> 1, wn = wv & 1;
  const int quad = lane >> 4, l15 = lane & 15;
  const int sr = t >> 1, sh = (t & 1) * 32;
  const int bn0 = blockIdx.x * 128, row0 = blockIdx.y * 128;

  floatx4 acc[4][4];
#pragma unroll
  for (int i = 0; i < 4; ++i)
#pragma unroll
    for (int j = 0; j < 4; ++j) acc[i][j] = {0.f, 0.f, 0.f, 0.f};

  const float* arow = attn + (size_t)(row0 + sr) * 256 + sh;
  const ushort* brow = BT + (size_t)(bn0 + sr) * 256 + sh;

  for (int kc = 0; kc < 4; ++kc) {
    const int k0 = kc * 64;
#pragma unroll
    for (int u = 0; u < 4; ++u) {
      float4 v0 = *(const float4*)(arow + k0 + u * 8);
      float4 v1 = *(const float4*)(arow + k0 + u * 8 + 4);
      ushort tmp[8] = {f2b(v0.x), f2b(v0.y), f2b(v0.z), f2b(v0.w),
                       f2b(v1.x), f2b(v1.y), f2b(v1.z), f2b(v1.w)};
      *(uint4*)&As[sr][sh + u * 8] = *(uint4*)tmp;
      *(uint4*)&Bs[sr][sh + u * 8] = *(const uint4*)(brow + k0 + u * 8);
    }
    __syncthreads();
#pragma unroll
    for (int ks = 0; ks < 2; ++ks) {
      const int ko = ks * 32 + quad * 8;
      short8 af[4], bf[4];
#pragma unroll
      for (int i = 0; i < 4; ++i) {
        af[i] = *(const short8*)&As[wm * 64 + i * 16 + l15][ko];
        bf[i] = *(const short8*)&Bs[wn * 64 + i * 16 + l15][ko];
      }
#pragma unroll
      for (int mi = 0; mi < 4; ++mi)
#pragma unroll
        for (int nj = 0; nj < 4; ++nj)
          acc[mi][nj] = __builtin_amdgcn_mfma_f32_16x16x32_bf16(
              af[mi], bf[nj], acc[mi][nj], 0, 0, 0);
    }
    __syncthreads();
  }

  float bias[4];
  int ncol[4];
#pragma unroll
  for (int nj = 0; nj < 4; ++nj) {
    ncol[nj] = bn0 + wn * 64 + nj * 16 + l15;
    bias[nj] = bo[ncol[nj]];
  }
#pragma unroll
  for (int mi = 0; mi < 4; ++mi)
#pragma unroll
    for (int r = 0; r < 4; ++r) {
      const int gr = row0 + wm * 64 + mi * 16 + quad * 4 + r;
      int m, h, w;
      win_coords(pass, w0 + (gr >> 6), gr & 63, m, h, w);
      float* orow = out + (size_t)((m * 64 + h) * 64 + w) * 256;
#pragma unroll
      for (int nj = 0; nj < 4; ++nj)
        orow[ncol[nj]] = acc[mi][nj][r] + bias[nj];
    }
}

// ---------------------------------------------------------------------------
extern "C" void kernel_launch(void* const* d_in, const int* in_sizes, int n_in,
                              void* d_out, int out_size, void* d_ws, size_t ws_size,
                              hipStream_t stream) {
  (void)in_sizes; (void)n_in; (void)out_size;
  const float* x    = (const float*)d_in[0];
  const float* wqkv = (const float*)d_in[1];
  const float* bqkv = (const float*)d_in[2];
  const float* wo   = (const float*)d_in[3];
  const float* bo   = (const float*)d_in[4];
  float* out = (float*)d_out;

  // ws layout: wqkvT(384K) | woT(128K) | xw(64M, all windows) | qkvh | attn
  ushort* wqkvT = (ushort*)d_ws;
  ushort* woT   = (ushort*)((char*)d_ws + 393216);
  ushort* xw    = (ushort*)((char*)d_ws + 524288);
  char* chunkbase = (char*)d_ws + 524288 + 67108864;
  size_t fixed = 524288 + 67108864;
  size_t rem = (ws_size > fixed) ? (ws_size - fixed) : 0;
  int S = 1;
  while (S < 1024 && (size_t)(2048 / S) * 163840 > rem) S <<= 1;
  const int CW = 2048 / S;
  ushort* qkvh   = (ushort*)chunkbase;                         // CW*98304 B
  float*  attnws = (float*)(chunkbase + (size_t)CW * 98304);   // CW*65536 B

  wtrans_kernel<<<dim3(1024), dim3(256), 0, stream>>>(wqkv, wo, wqkvT, woT);

  for (int pass = 0; pass < 2; ++pass) {
    const float* src = pass ? (const float*)out : x;
    convert_kernel<<<dim3(16384), dim3(256), 0, stream>>>(src, xw, pass);
    for (int c = 0; c < S; ++c) {
      const int w0 = c * CW;
      qkv_mfma_kernel<<<dim3(6, CW / 2), dim3(256), 0, stream>>>(
          xw + (size_t)w0 * 64 * 256, wqkvT, bqkv, qkvh);
      attn_kernel<<<dim3(CW * 8), dim3(256), 0, stream>>>(
          qkvh, attnws, w0, pass);
      proj_mfma_kernel<<<dim3(2, CW / 2), dim3(256), 0, stream>>>(
          attnws, woT, bo, out, w0, pass);
    }
  }
}

// Round 3
// 857.717 us; speedup vs baseline: 3.9400x; 1.9593x over previous
//
#include <hip/hip_runtime.h>
#include <hip/hip_bf16.h>

// SWIN attention, round 3: MFMA everywhere. Per-wave attention, no barriers.
// qkvh layout per window (bf16): [head]Q[64s][32d] | [head]K[64s][32d] | [head]V^T[32d][64s]
//   Q at head*2048, K at (8+head)*2048, V^T at (16+head)*2048; win stride 49152.

typedef short short8 __attribute__((ext_vector_type(8)));
typedef float floatx4 __attribute__((ext_vector_type(4)));

#define SCALE 0.17677669529663687f  // 1/sqrt(32)
#define NEGM  -1e9f

__device__ __forceinline__ void win_coords(int pass, int gw, int s,
                                           int& m, int& h, int& w) {
  m = gw >> 6;
  int wy = (gw >> 3) & 7, wx = gw & 7;
  h = wy * 8 + (s >> 3);
  w = wx * 8 + (s & 7);
  if (pass) { h = (h + 4) & 63; w = (w + 4) & 63; }
}

__device__ __forceinline__ int region_id(int wy, int wx, int s) {
  int rh = (wy == 7) ? (((s >> 3) >= 4) ? 2 : 1) : 0;
  int rw = (wx == 7) ? (((s & 7) >= 4) ? 2 : 1) : 0;
  return rh * 3 + rw;
}

__device__ __forceinline__ ushort f2b(float f) {  // RNE fp32->bf16
  uint u = __float_as_uint(f);
  return (ushort)((u + 0x7FFFu + ((u >> 16) & 1u)) >> 16);
}

// ---------------------------------------------------------------------------
// K0: weights -> k-contiguous bf16.
// ---------------------------------------------------------------------------
__global__ __launch_bounds__(256) void wtrans_kernel(
    const float* __restrict__ wqkv, const float* __restrict__ wo,
    ushort* __restrict__ wqkvT, ushort* __restrict__ woT) {
  const int t = threadIdx.x, b = blockIdx.x;
  if (b < 768) {
    wqkvT[b * 256 + t] = f2b(wqkv[t * 768 + b]);
  } else {
    const int n = b - 768;
    woT[n * 256 + t] = f2b(wo[t * 256 + n]);
  }
}

// ---------------------------------------------------------------------------
// K1: gather window tokens (with pass-2 roll) + fp32->bf16.
// ---------------------------------------------------------------------------
__global__ __launch_bounds__(256) void convert_kernel(
    const float* __restrict__ src, ushort* __restrict__ xw, int pass) {
  const int t = threadIdx.x;
  const int row = blockIdx.x * 8 + (t >> 5);
  const int c = (t & 31) * 8;
  int m, h, w;
  win_coords(pass, row >> 6, row & 63, m, h, w);
  const float* s = src + (size_t)((m * 64 + h) * 64 + w) * 256 + c;
  float4 a = *(const float4*)s;
  float4 b = *(const float4*)(s + 4);
  ushort o[8] = {f2b(a.x), f2b(a.y), f2b(a.z), f2b(a.w),
                 f2b(b.x), f2b(b.y), f2b(b.z), f2b(b.w)};
  *(uint4*)(xw + (size_t)row * 256 + c) = *(uint4*)o;
}

// ---------------------------------------------------------------------------
// K2: qkv GEMM -> head-major bf16 with V stored transposed.
// ---------------------------------------------------------------------------
__global__ __launch_bounds__(256) void qkv_mfma_kernel(
    const ushort* __restrict__ A, const ushort* __restrict__ BT,
    const float* __restrict__ bqkv, ushort* __restrict__ qkvh) {
  __shared__ ushort As[128][72];
  __shared__ ushort Bs[128][72];
  const int t = threadIdx.x;
  const int lane = t & 63, wv = t >> 6;
  const int wm = wv >> 1, wn = wv & 1;
  const int quad = lane >> 4, l15 = lane & 15;
  const int sr = t >> 1, sh = (t & 1) * 32;
  const int bn0 = blockIdx.x * 128, row0 = blockIdx.y * 128;

  floatx4 acc[4][4];
#pragma unroll
  for (int i = 0; i < 4; ++i)
#pragma unroll
    for (int j = 0; j < 4; ++j) acc[i][j] = {0.f, 0.f, 0.f, 0.f};

  const ushort* arow = A + (size_t)(row0 + sr) * 256 + sh;
  const ushort* brow = BT + (size_t)(bn0 + sr) * 256 + sh;

  for (int kc = 0; kc < 4; ++kc) {
    const int k0 = kc * 64;
#pragma unroll
    for (int u = 0; u < 4; ++u) {
      *(uint4*)&As[sr][sh + u * 8] = *(const uint4*)(arow + k0 + u * 8);
      *(uint4*)&Bs[sr][sh + u * 8] = *(const uint4*)(brow + k0 + u * 8);
    }
    __syncthreads();
#pragma unroll
    for (int ks = 0; ks < 2; ++ks) {
      const int ko = ks * 32 + quad * 8;
      short8 af[4], bf[4];
#pragma unroll
      for (int i = 0; i < 4; ++i) {
        af[i] = *(const short8*)&As[wm * 64 + i * 16 + l15][ko];
        bf[i] = *(const short8*)&Bs[wn * 64 + i * 16 + l15][ko];
      }
#pragma unroll
      for (int mi = 0; mi < 4; ++mi)
#pragma unroll
        for (int nj = 0; nj < 4; ++nj)
          acc[mi][nj] = __builtin_amdgcn_mfma_f32_16x16x32_bf16(
              af[mi], bf[nj], acc[mi][nj], 0, 0, 0);
    }
    __syncthreads();
  }

  // epilogue: +bias, bf16, head-major scatter; V block transposed.
  int off_n[4], sm_n[4];
  float bias[4];
#pragma unroll
  for (int nj = 0; nj < 4; ++nj) {
    const int n = bn0 + wn * 64 + nj * 16 + l15;
    const int which = n >> 8, head = (n >> 5) & 7, d = n & 31;
    if (which == 2) { off_n[nj] = (16 + head) * 2048 + d * 64; sm_n[nj] = 1; }
    else           { off_n[nj] = (which * 8 + head) * 2048 + d; sm_n[nj] = 32; }
    bias[nj] = bqkv[n];
  }
#pragma unroll
  for (int mi = 0; mi < 4; ++mi)
#pragma unroll
    for (int r = 0; r < 4; ++r) {
      const int gr = row0 + wm * 64 + mi * 16 + quad * 4 + r;
      ushort* base = qkvh + (size_t)(gr >> 6) * 49152;
      const int s = gr & 63;
#pragma unroll
      for (int nj = 0; nj < 4; ++nj)
        base[off_n[nj] + s * sm_n[nj]] = f2b(acc[mi][nj][r] + bias[nj]);
    }
}

// ---------------------------------------------------------------------------
// K3: per-wave MFMA attention, no barriers. One wave = one (window, head).
// grid CW*2 blocks x 256 threads (4 waves).
// ---------------------------------------------------------------------------
__global__ __launch_bounds__(256) void attn_mfma_kernel(
    const ushort* __restrict__ qkvh, ushort* __restrict__ attn_out,
    int w0, int pass) {
  __shared__ ushort Pt[4][64][72];  // per-wave P (bf16), 16B-aligned rows
  const int t = threadIdx.x;
  const int wv = t >> 6, lane = t & 63;
  const int quad = lane >> 4, l15 = lane & 15;
  const int task = blockIdx.x * 4 + wv;
  const int wi = task >> 3, hh = task & 7;
  const ushort* qb = qkvh + (size_t)wi * 49152 + hh * 2048;
  const ushort* kb = qb + 16384;
  const ushort* vtb = qb + 32768;

  // QK^T: direct-from-global fragments
  short8 qf[4], kf[4];
#pragma unroll
  for (int i = 0; i < 4; ++i) {
    qf[i] = *(const short8*)(qb + (i * 16 + l15) * 32 + quad * 8);
    kf[i] = *(const short8*)(kb + (i * 16 + l15) * 32 + quad * 8);
  }
  floatx4 S[4][4];
#pragma unroll
  for (int i = 0; i < 4; ++i)
#pragma unroll
    for (int j = 0; j < 4; ++j) S[i][j] = {0.f, 0.f, 0.f, 0.f};
#pragma unroll
  for (int mi = 0; mi < 4; ++mi)
#pragma unroll
    for (int nj = 0; nj < 4; ++nj)
      S[mi][nj] = __builtin_amdgcn_mfma_f32_16x16x32_bf16(
          qf[mi], kf[nj], S[mi][nj], 0, 0, 0);

  // scale + swin mask
  const int gw = w0 + wi;
  const int wy = (gw >> 3) & 7, wx = gw & 7;
#pragma unroll
  for (int mi = 0; mi < 4; ++mi)
#pragma unroll
    for (int nj = 0; nj < 4; ++nj)
#pragma unroll
      for (int r = 0; r < 4; ++r) S[mi][nj][r] *= SCALE;
  if (pass) {
    int ridc[4];
#pragma unroll
    for (int nj = 0; nj < 4; ++nj) ridc[nj] = region_id(wy, wx, nj * 16 + l15);
#pragma unroll
    for (int mi = 0; mi < 4; ++mi)
#pragma unroll
      for (int r = 0; r < 4; ++r) {
        const int rr = region_id(wy, wx, mi * 16 + quad * 4 + r);
#pragma unroll
        for (int nj = 0; nj < 4; ++nj)
          if (rr != ridc[nj]) S[mi][nj][r] += NEGM;
      }
  }

  // softmax per row (row = mi*16+quad*4+r, spread over 16 lanes l15 x 4 nj)
#pragma unroll
  for (int mi = 0; mi < 4; ++mi) {
#pragma unroll
    for (int r = 0; r < 4; ++r) {
      float mx = fmaxf(fmaxf(S[mi][0][r], S[mi][1][r]),
                       fmaxf(S[mi][2][r], S[mi][3][r]));
#pragma unroll
      for (int o = 1; o < 16; o <<= 1) mx = fmaxf(mx, __shfl_xor(mx, o));
      float sm = 0.f;
#pragma unroll
      for (int nj = 0; nj < 4; ++nj) {
        float e = __expf(S[mi][nj][r] - mx);
        S[mi][nj][r] = e;
        sm += e;
      }
#pragma unroll
      for (int o = 1; o < 16; o <<= 1) sm += __shfl_xor(sm, o);
      const float inv = 1.f / sm;
#pragma unroll
      for (int nj = 0; nj < 4; ++nj) {
        const int row = mi * 16 + quad * 4 + r;
        Pt[wv][row][nj * 16 + l15] = f2b(S[mi][nj][r] * inv);
      }
    }
  }

  // PV: A = P from LDS (A-layout), B = V^T from global
  floatx4 O[4][2];
#pragma unroll
  for (int i = 0; i < 4; ++i) {
    O[i][0] = {0.f, 0.f, 0.f, 0.f};
    O[i][1] = {0.f, 0.f, 0.f, 0.f};
  }
#pragma unroll
  for (int ks = 0; ks < 2; ++ks) {
    short8 bfr[2];
#pragma unroll
    for (int n2 = 0; n2 < 2; ++n2)
      bfr[n2] = *(const short8*)(vtb + (n2 * 16 + l15) * 64 + ks * 32 + quad * 8);
#pragma unroll
    for (int mi = 0; mi < 4; ++mi) {
      short8 af = *(const short8*)&Pt[wv][mi * 16 + l15][ks * 32 + quad * 8];
#pragma unroll
      for (int n2 = 0; n2 < 2; ++n2)
        O[mi][n2] = __builtin_amdgcn_mfma_f32_16x16x32_bf16(
            af, bfr[n2], O[mi][n2], 0, 0, 0);
    }
  }

  // store bf16 [win][s][256]
  ushort* ob = attn_out + (size_t)wi * 16384 + hh * 32;
#pragma unroll
  for (int mi = 0; mi < 4; ++mi)
#pragma unroll
    for (int r = 0; r < 4; ++r) {
      const int s = mi * 16 + quad * 4 + r;
      ob[s * 256 + l15]      = f2b(O[mi][0][r]);
      ob[s * 256 + 16 + l15] = f2b(O[mi][1][r]);
    }
}

// ---------------------------------------------------------------------------
// K4: out-proj GEMM (bf16 A), fused window-reverse(+roll) scatter.
// ---------------------------------------------------------------------------
__global__ __launch_bounds__(256) void proj_mfma_kernel(
    const ushort* __restrict__ attn, const ushort* __restrict__ BT,
    const float* __restrict__ bo, float* __restrict__ out,
    int w0, int pass) {
  __shared__ ushort As[128][72];
  __shared__ ushort Bs[128][72];
  const int t = threadIdx.x;
  const int lane = t & 63, wv = t >> 6;
  const int wm = wv >> 1, wn = wv & 1;
  const int quad = lane >> 4, l15 = lane & 15;
  const int sr = t >> 1, sh = (t & 1) * 32;
  const int bn0 = blockIdx.x * 128, row0 = blockIdx.y * 128;

  floatx4 acc[4][4];
#pragma unroll
  for (int i = 0; i < 4; ++i)
#pragma unroll
    for (int j = 0; j < 4; ++j) acc[i][j] = {0.f, 0.f, 0.f, 0.f};

  const ushort* arow = attn + (size_t)(row0 + sr) * 256 + sh;
  const ushort* brow = BT + (size_t)(bn0 + sr) * 256 + sh;

  for (int kc = 0; kc < 4; ++kc) {
    const int k0 = kc * 64;
#pragma unroll
    for (int u = 0; u < 4; ++u) {
      *(uint4*)&As[sr][sh + u * 8] = *(const uint4*)(arow + k0 + u * 8);
      *(uint4*)&Bs[sr][sh + u * 8] = *(const uint4*)(brow + k0 + u * 8);
    }
    __syncthreads();
#pragma unroll
    for (int ks = 0; ks < 2; ++ks) {
      const int ko = ks * 32 + quad * 8;
      short8 af[4], bf[4];
#pragma unroll
      for (int i = 0; i < 4; ++i) {
        af[i] = *(const short8*)&As[wm * 64 + i * 16 + l15][ko];
        bf[i] = *(const short8*)&Bs[wn * 64 + i * 16 + l15][ko];
      }
#pragma unroll
      for (int mi = 0; mi < 4; ++mi)
#pragma unroll
        for (int nj = 0; nj < 4; ++nj)
          acc[mi][nj] = __builtin_amdgcn_mfma_f32_16x16x32_bf16(
              af[mi], bf[nj], acc[mi][nj], 0, 0, 0);
    }
    __syncthreads();
  }

  float bias[4];
  int ncol[4];
#pragma unroll
  for (int nj = 0; nj < 4; ++nj) {
    ncol[nj] = bn0 + wn * 64 + nj * 16 + l15;
    bias[nj] = bo[ncol[nj]];
  }
#pragma unroll
  for (int mi = 0; mi < 4; ++mi)
#pragma unroll
    for (int r = 0; r < 4; ++r) {
      const int gr = row0 + wm * 64 + mi * 16 + quad * 4 + r;
      int m, h, w;
      win_coords(pass, w0 + (gr >> 6), gr & 63, m, h, w);
      float* orow = out + (size_t)((m * 64 + h) * 64 + w) * 256;
#pragma unroll
      for (int nj = 0; nj < 4; ++nj)
        orow[ncol[nj]] = acc[mi][nj][r] + bias[nj];
    }
}

// ---------------------------------------------------------------------------
extern "C" void kernel_launch(void* const* d_in, const int* in_sizes, int n_in,
                              void* d_out, int out_size, void* d_ws, size_t ws_size,
                              hipStream_t stream) {
  (void)in_sizes; (void)n_in; (void)out_size;
  const float* x    = (const float*)d_in[0];
  const float* wqkv = (const float*)d_in[1];
  const float* bqkv = (const float*)d_in[2];
  const float* wo   = (const float*)d_in[3];
  const float* bo   = (const float*)d_in[4];
  float* out = (float*)d_out;

  // ws: wqkvT(384K) | woT(128K) | xw(64M) | qkvh(CW*96K) | attn bf16(CW*32K)
  ushort* wqkvT = (ushort*)d_ws;
  ushort* woT   = (ushort*)((char*)d_ws + 393216);
  ushort* xw    = (ushort*)((char*)d_ws + 524288);
  char* chunkbase = (char*)d_ws + 524288 + 67108864;
  size_t fixed = 524288 + 67108864;
  size_t rem = (ws_size > fixed) ? (ws_size - fixed) : 0;
  int S = 1;
  while (S < 1024 && (size_t)(2048 / S) * 131072 > rem) S <<= 1;
  const int CW = 2048 / S;
  ushort* qkvh   = (ushort*)chunkbase;                          // CW*98304 B
  ushort* attnws = (ushort*)(chunkbase + (size_t)CW * 98304);   // CW*32768 B

  wtrans_kernel<<<dim3(1024), dim3(256), 0, stream>>>(wqkv, wo, wqkvT, woT);

  for (int pass = 0; pass < 2; ++pass) {
    const float* src = pass ? (const float*)out : x;
    convert_kernel<<<dim3(16384), dim3(256), 0, stream>>>(src, xw, pass);
    for (int c = 0; c < S; ++c) {
      const int w0 = c * CW;
      qkv_mfma_kernel<<<dim3(6, CW / 2), dim3(256), 0, stream>>>(
          xw + (size_t)w0 * 64 * 256, wqkvT, bqkv, qkvh);
      attn_mfma_kernel<<<dim3(CW * 2), dim3(256), 0, stream>>>(
          qkvh, attnws, w0, pass);
      proj_mfma_kernel<<<dim3(2, CW / 2), dim3(256), 0, stream>>>(
          attnws, woT, bo, out, w0, pass);
    }
  }
}

// Round 4
// 696.028 us; speedup vs baseline: 4.8553x; 1.2323x over previous
//
#include <hip/hip_runtime.h>
#include <hip/hip_bf16.h>

// SWIN attention, round 4: fused per-head QKV-GEMM + attention (no qkvh
// intermediate). Pipeline per pass: convert(bf16 gather) -> qkvattn -> proj.
// qkvattn: block = 4 waves = heads {0-3} or {4-7} of one window; each wave
// computes Q,K,V (64x96 GEMM, K=256) into wave-private LDS, then QK^T ->
// softmax -> PV with MFMA. No __syncthreads anywhere in the kernel.

typedef short short8 __attribute__((ext_vector_type(8)));
typedef float floatx4 __attribute__((ext_vector_type(4)));

#define SCALE 0.17677669529663687f  // 1/sqrt(32)
#define NEGM  -1e9f

__device__ __forceinline__ void win_coords(int pass, int gw, int s,
                                           int& m, int& h, int& w) {
  m = gw >> 6;
  int wy = (gw >> 3) & 7, wx = gw & 7;
  h = wy * 8 + (s >> 3);
  w = wx * 8 + (s & 7);
  if (pass) { h = (h + 4) & 63; w = (w + 4) & 63; }
}

__device__ __forceinline__ int region_id(int wy, int wx, int s) {
  int rh = (wy == 7) ? (((s >> 3) >= 4) ? 2 : 1) : 0;
  int rw = (wx == 7) ? (((s & 7) >= 4) ? 2 : 1) : 0;
  return rh * 3 + rw;
}

__device__ __forceinline__ ushort f2b(float f) {  // RNE fp32->bf16
  uint u = __float_as_uint(f);
  return (ushort)((u + 0x7FFFu + ((u >> 16) & 1u)) >> 16);
}

// ---------------------------------------------------------------------------
// K0: weights -> k-contiguous bf16.
// ---------------------------------------------------------------------------
__global__ __launch_bounds__(256) void wtrans_kernel(
    const float* __restrict__ wqkv, const float* __restrict__ wo,
    ushort* __restrict__ wqkvT, ushort* __restrict__ woT) {
  const int t = threadIdx.x, b = blockIdx.x;
  if (b < 768) {
    wqkvT[b * 256 + t] = f2b(wqkv[t * 768 + b]);
  } else {
    const int n = b - 768;
    woT[n * 256 + t] = f2b(wo[t * 256 + n]);
  }
}

// ---------------------------------------------------------------------------
// K1: gather window tokens (with pass-2 roll) + fp32->bf16.
// ---------------------------------------------------------------------------
__global__ __launch_bounds__(256) void convert_kernel(
    const float* __restrict__ src, ushort* __restrict__ xw, int pass) {
  const int t = threadIdx.x;
  const int row = blockIdx.x * 8 + (t >> 5);
  const int c = (t & 31) * 8;
  int m, h, w;
  win_coords(pass, row >> 6, row & 63, m, h, w);
  const float* s = src + (size_t)((m * 64 + h) * 64 + w) * 256 + c;
  float4 a = *(const float4*)s;
  float4 b = *(const float4*)(s + 4);
  ushort o[8] = {f2b(a.x), f2b(a.y), f2b(a.z), f2b(a.w),
                 f2b(b.x), f2b(b.y), f2b(b.z), f2b(b.w)};
  *(uint4*)(xw + (size_t)row * 256 + c) = *(uint4*)o;
}

// ---------------------------------------------------------------------------
// K2: fused qkv + attention. grid CW*2 x 256 (4 waves = 4 heads).
// Wave-private LDS per wave (ushort units):
//   Qs [64][40] at 0     (2560)
//   Ks [64][40] at 2560  (2560)
//   Vt [32][72] at 5120  (2304)  -> total 7424/wave
//   Ps [64][72] aliases Qs+Ks (4608 <= 5120, both dead after QK^T frags load)
// ---------------------------------------------------------------------------
__global__ __launch_bounds__(256, 2) void qkvattn_kernel(
    const ushort* __restrict__ xw, const ushort* __restrict__ wqkvT,
    const float* __restrict__ bqkv, ushort* __restrict__ attn_out,
    int w0, int pass) {
  __shared__ ushort sm[4][7424];
  const int t = threadIdx.x;
  const int wv = t >> 6, lane = t & 63;
  const int quad = lane >> 4, l15 = lane & 15;
  const int wi = blockIdx.x >> 1;
  const int hh = (blockIdx.x & 1) * 4 + wv;
  const ushort* xwin = xw + (size_t)wi * 16384;
  ushort* Qs = sm[wv];
  ushort* Ks = sm[wv] + 2560;
  ushort* Vt = sm[wv] + 5120;
  ushort* Ps = sm[wv];

  // ---- qkv GEMM for this head: M=64 tok, N=96 (Q|K|V x 32d), K=256 ----
  floatx4 acc[4][6];
#pragma unroll
  for (int i = 0; i < 4; ++i)
#pragma unroll
    for (int j = 0; j < 6; ++j) acc[i][j] = {0.f, 0.f, 0.f, 0.f};

  const ushort* brow[6];
#pragma unroll
  for (int nt = 0; nt < 6; ++nt) {
    const int n = (nt >> 1) * 256 + hh * 32 + (nt & 1) * 16 + l15;
    brow[nt] = wqkvT + (size_t)n * 256;
  }

#pragma unroll
  for (int ks = 0; ks < 8; ++ks) {
    const int k0 = ks * 32 + quad * 8;
    short8 af[4], bf[6];
#pragma unroll
    for (int mi = 0; mi < 4; ++mi)
      af[mi] = *(const short8*)(xwin + (mi * 16 + l15) * 256 + k0);
#pragma unroll
    for (int nt = 0; nt < 6; ++nt)
      bf[nt] = *(const short8*)(brow[nt] + k0);
#pragma unroll
    for (int mi = 0; mi < 4; ++mi)
#pragma unroll
      for (int nt = 0; nt < 6; ++nt)
        acc[mi][nt] = __builtin_amdgcn_mfma_f32_16x16x32_bf16(
            af[mi], bf[nt], acc[mi][nt], 0, 0, 0);
  }

  // epilogue: +bias, bf16, into wave-private LDS (Q/K row-major, V transposed)
#pragma unroll
  for (int nt = 0; nt < 6; ++nt) {
    const float bias = bqkv[(nt >> 1) * 256 + hh * 32 + (nt & 1) * 16 + l15];
    const int d = (nt & 1) * 16 + l15;
#pragma unroll
    for (int mi = 0; mi < 4; ++mi)
#pragma unroll
      for (int r = 0; r < 4; ++r) {
        const int tok = mi * 16 + quad * 4 + r;
        const ushort v = f2b(acc[mi][nt][r] + bias);
        if (nt < 2)      Qs[tok * 40 + d] = v;
        else if (nt < 4) Ks[tok * 40 + d] = v;
        else             Vt[d * 72 + tok] = v;
      }
  }

  // ---- QK^T (frags from wave-private LDS) ----
  short8 qf[4], kf[4];
#pragma unroll
  for (int i = 0; i < 4; ++i) {
    qf[i] = *(const short8*)&Qs[(i * 16 + l15) * 40 + quad * 8];
    kf[i] = *(const short8*)&Ks[(i * 16 + l15) * 40 + quad * 8];
  }
  floatx4 S[4][4];
#pragma unroll
  for (int i = 0; i < 4; ++i)
#pragma unroll
    for (int j = 0; j < 4; ++j) S[i][j] = {0.f, 0.f, 0.f, 0.f};
#pragma unroll
  for (int mi = 0; mi < 4; ++mi)
#pragma unroll
    for (int nj = 0; nj < 4; ++nj)
      S[mi][nj] = __builtin_amdgcn_mfma_f32_16x16x32_bf16(
          qf[mi], kf[nj], S[mi][nj], 0, 0, 0);

  // scale + swin mask
  const int gw = w0 + wi;
  const int wy = (gw >> 3) & 7, wx = gw & 7;
#pragma unroll
  for (int mi = 0; mi < 4; ++mi)
#pragma unroll
    for (int nj = 0; nj < 4; ++nj)
#pragma unroll
      for (int r = 0; r < 4; ++r) S[mi][nj][r] *= SCALE;
  if (pass) {
    int ridc[4];
#pragma unroll
    for (int nj = 0; nj < 4; ++nj) ridc[nj] = region_id(wy, wx, nj * 16 + l15);
#pragma unroll
    for (int mi = 0; mi < 4; ++mi)
#pragma unroll
      for (int r = 0; r < 4; ++r) {
        const int rr = region_id(wy, wx, mi * 16 + quad * 4 + r);
#pragma unroll
        for (int nj = 0; nj < 4; ++nj)
          if (rr != ridc[nj]) S[mi][nj][r] += NEGM;
      }
  }

  // softmax per row; write P (bf16) to Ps (aliases Q/K region, now dead)
#pragma unroll
  for (int mi = 0; mi < 4; ++mi) {
#pragma unroll
    for (int r = 0; r < 4; ++r) {
      float mx = fmaxf(fmaxf(S[mi][0][r], S[mi][1][r]),
                       fmaxf(S[mi][2][r], S[mi][3][r]));
#pragma unroll
      for (int o = 1; o < 16; o <<= 1) mx = fmaxf(mx, __shfl_xor(mx, o));
      float sm_ = 0.f;
#pragma unroll
      for (int nj = 0; nj < 4; ++nj) {
        float e = __expf(S[mi][nj][r] - mx);
        S[mi][nj][r] = e;
        sm_ += e;
      }
#pragma unroll
      for (int o = 1; o < 16; o <<= 1) sm_ += __shfl_xor(sm_, o);
      const float inv = 1.f / sm_;
      const int row = mi * 16 + quad * 4 + r;
#pragma unroll
      for (int nj = 0; nj < 4; ++nj)
        Ps[row * 72 + nj * 16 + l15] = f2b(S[mi][nj][r] * inv);
    }
  }

  // ---- PV: A = P (LDS), B = V^T (LDS) ----
  floatx4 O[4][2];
#pragma unroll
  for (int i = 0; i < 4; ++i) {
    O[i][0] = {0.f, 0.f, 0.f, 0.f};
    O[i][1] = {0.f, 0.f, 0.f, 0.f};
  }
#pragma unroll
  for (int ks = 0; ks < 2; ++ks) {
    short8 bfr[2];
#pragma unroll
    for (int n2 = 0; n2 < 2; ++n2)
      bfr[n2] = *(const short8*)&Vt[(n2 * 16 + l15) * 72 + ks * 32 + quad * 8];
#pragma unroll
    for (int mi = 0; mi < 4; ++mi) {
      short8 af = *(const short8*)&Ps[(mi * 16 + l15) * 72 + ks * 32 + quad * 8];
#pragma unroll
      for (int n2 = 0; n2 < 2; ++n2)
        O[mi][n2] = __builtin_amdgcn_mfma_f32_16x16x32_bf16(
            af, bfr[n2], O[mi][n2], 0, 0, 0);
    }
  }

  // store bf16 [win][tok][256]
  ushort* ob = attn_out + (size_t)wi * 16384 + hh * 32;
#pragma unroll
  for (int mi = 0; mi < 4; ++mi)
#pragma unroll
    for (int r = 0; r < 4; ++r) {
      const int s = mi * 16 + quad * 4 + r;
      ob[s * 256 + l15]      = f2b(O[mi][0][r]);
      ob[s * 256 + 16 + l15] = f2b(O[mi][1][r]);
    }
}

// ---------------------------------------------------------------------------
// K3: out-proj GEMM (bf16 A), fused window-reverse(+roll) scatter.
// ---------------------------------------------------------------------------
__global__ __launch_bounds__(256) void proj_mfma_kernel(
    const ushort* __restrict__ attn, const ushort* __restrict__ BT,
    const float* __restrict__ bo, float* __restrict__ out,
    int w0, int pass) {
  __shared__ ushort As[128][72];
  __shared__ ushort Bs[128][72];
  const int t = threadIdx.x;
  const int lane = t & 63, wv = t >> 6;
  const int wm = wv >> 1, wn = wv & 1;
  const int quad = lane >> 4, l15 = lane & 15;
  const int sr = t >> 1, sh = (t & 1) * 32;
  const int bn0 = blockIdx.x * 128, row0 = blockIdx.y * 128;

  floatx4 acc[4][4];
#pragma unroll
  for (int i = 0; i < 4; ++i)
#pragma unroll
    for (int j = 0; j < 4; ++j) acc[i][j] = {0.f, 0.f, 0.f, 0.f};

  const ushort* arow = attn + (size_t)(row0 + sr) * 256 + sh;
  const ushort* brow = BT + (size_t)(bn0 + sr) * 256 + sh;

  for (int kc = 0; kc < 4; ++kc) {
    const int k0 = kc * 64;
#pragma unroll
    for (int u = 0; u < 4; ++u) {
      *(uint4*)&As[sr][sh + u * 8] = *(const uint4*)(arow + k0 + u * 8);
      *(uint4*)&Bs[sr][sh + u * 8] = *(const uint4*)(brow + k0 + u * 8);
    }
    __syncthreads();
#pragma unroll
    for (int ks = 0; ks < 2; ++ks) {
      const int ko = ks * 32 + quad * 8;
      short8 af[4], bf[4];
#pragma unroll
      for (int i = 0; i < 4; ++i) {
        af[i] = *(const short8*)&As[wm * 64 + i * 16 + l15][ko];
        bf[i] = *(const short8*)&Bs[wn * 64 + i * 16 + l15][ko];
      }
#pragma unroll
      for (int mi = 0; mi < 4; ++mi)
#pragma unroll
        for (int nj = 0; nj < 4; ++nj)
          acc[mi][nj] = __builtin_amdgcn_mfma_f32_16x16x32_bf16(
              af[mi], bf[nj], acc[mi][nj], 0, 0, 0);
    }
    __syncthreads();
  }

  float bias[4];
  int ncol[4];
#pragma unroll
  for (int nj = 0; nj < 4; ++nj) {
    ncol[nj] = bn0 + wn * 64 + nj * 16 + l15;
    bias[nj] = bo[ncol[nj]];
  }
#pragma unroll
  for (int mi = 0; mi < 4; ++mi)
#pragma unroll
    for (int r = 0; r < 4; ++r) {
      const int gr = row0 + wm * 64 + mi * 16 + quad * 4 + r;
      int m, h, w;
      win_coords(pass, w0 + (gr >> 6), gr & 63, m, h, w);
      float* orow = out + (size_t)((m * 64 + h) * 64 + w) * 256;
#pragma unroll
      for (int nj = 0; nj < 4; ++nj)
        orow[ncol[nj]] = acc[mi][nj][r] + bias[nj];
    }
}

// ---------------------------------------------------------------------------
extern "C" void kernel_launch(void* const* d_in, const int* in_sizes, int n_in,
                              void* d_out, int out_size, void* d_ws, size_t ws_size,
                              hipStream_t stream) {
  (void)in_sizes; (void)n_in; (void)out_size;
  const float* x    = (const float*)d_in[0];
  const float* wqkv = (const float*)d_in[1];
  const float* bqkv = (const float*)d_in[2];
  const float* wo   = (const float*)d_in[3];
  const float* bo   = (const float*)d_in[4];
  float* out = (float*)d_out;

  // ws: wqkvT(384K) | woT(128K) | xw(64M) | attn bf16 (CW*32K)
  ushort* wqkvT = (ushort*)d_ws;
  ushort* woT   = (ushort*)((char*)d_ws + 393216);
  ushort* xw    = (ushort*)((char*)d_ws + 524288);
  char* chunkbase = (char*)d_ws + 524288 + 67108864;
  size_t fixed = 524288 + 67108864;
  size_t rem = (ws_size > fixed) ? (ws_size - fixed) : 0;
  int S = 1;
  while (S < 1024 && (size_t)(2048 / S) * 32768 > rem) S <<= 1;
  const int CW = 2048 / S;
  ushort* attnws = (ushort*)chunkbase;  // CW*32768 B

  wtrans_kernel<<<dim3(1024), dim3(256), 0, stream>>>(wqkv, wo, wqkvT, woT);

  for (int pass = 0; pass < 2; ++pass) {
    const float* src = pass ? (const float*)out : x;
    convert_kernel<<<dim3(16384), dim3(256), 0, stream>>>(src, xw, pass);
    for (int c = 0; c < S; ++c) {
      const int w0 = c * CW;
      qkvattn_kernel<<<dim3(CW * 2), dim3(256), 0, stream>>>(
          xw + (size_t)w0 * 16384, wqkvT, bqkv, attnws, w0, pass);
      proj_mfma_kernel<<<dim3(2, CW / 2), dim3(256), 0, stream>>>(
          attnws, woT, bo, out, w0, pass);
    }
  }
}